// Round 1
// baseline (769.722 us; speedup 1.0000x reference)
//
#include <hip/hip_runtime.h>
#include <hip/hip_bf16.h>

#define BATCH 65536
#define DK 512
#define DV 512
#define DH 64
#define BM 32

typedef __attribute__((ext_vector_type(8))) short bf16x8;
typedef __attribute__((ext_vector_type(4))) float f32x4;

__device__ __forceinline__ short f2bf(float f) {
    union { __hip_bfloat16 h; short s; } u;
    u.h = __float2bfloat16(f);
    return u.s;
}

__device__ __forceinline__ bf16x8 pack8(float4 a, float4 b) {
    bf16x8 r;
    r[0] = f2bf(a.x); r[1] = f2bf(a.y); r[2] = f2bf(a.z); r[3] = f2bf(a.w);
    r[4] = f2bf(b.x); r[5] = f2bf(b.y); r[6] = f2bf(b.z); r[7] = f2bf(b.w);
    return r;
}

// load 8 consecutive f32 and convert to a bf16x8 MFMA fragment
__device__ __forceinline__ bf16x8 loadB8(const float* __restrict__ p) {
    float4 a = *reinterpret_cast<const float4*>(p);
    float4 b = *reinterpret_cast<const float4*>(p + 4);
    return pack8(a, b);
}

// swizzled LDS A-fragment read: 16B at (row, kbyte), byte ^= (row&7)<<4
__device__ __forceinline__ bf16x8 ldsA(const char* base, int row, int kbyte, int stride) {
    int byte = row * stride + kbyte;
    byte ^= (row & 7) << 4;
    return *reinterpret_cast<const bf16x8*>(base + byte);
}

__global__ __launch_bounds__(256) void fused_free_energy(
    const float* __restrict__ key, const float* __restrict__ value,
    const float* __restrict__ W1, const float* __restrict__ b1,
    const float* __restrict__ W2, const float* __restrict__ b2,
    const float* __restrict__ Wp, const float* __restrict__ pb,
    float* __restrict__ outF, float* __restrict__ outPred,
    float* __restrict__ outPrec, float* __restrict__ outErr)
{
    __shared__ short keybS[BM * DK];   // 32 KB, bf16, XOR-swizzled rows
    __shared__ short hbS[BM * DH];     // 4 KB, bf16, XOR-swizzled rows
    __shared__ float fpart[4][BM];     // per-wave row partials of F

    char* kbase = reinterpret_cast<char*>(keybS);
    char* hbase = reinterpret_cast<char*>(hbS);

    const int tid  = threadIdx.x;
    const int wave = tid >> 6;
    const int lane = tid & 63;
    const int lh   = lane & 15;   // 0..15
    const int lg   = lane >> 4;   // 0..3
    const long row0 = (long)blockIdx.x * BM;

    // ---- stage key tile (BM x DK) f32 -> bf16 into swizzled LDS ----
    {
        const float4* kin = reinterpret_cast<const float4*>(key + row0 * DK);
        #pragma unroll
        for (int i = 0; i < (BM * DK / 4) / 256; ++i) {   // 16 iters
            int idx = i * 256 + tid;
            int r  = idx >> 7;       // DK/4 = 128 float4 per row
            int c4 = idx & 127;
            float4 v = kin[idx];
            short4 s;
            s.x = f2bf(v.x); s.y = f2bf(v.y); s.z = f2bf(v.z); s.w = f2bf(v.w);
            int byte = (r * DK + c4 * 4) * 2;
            byte ^= (r & 7) << 4;
            *reinterpret_cast<short4*>(kbase + byte) = s;
        }
    }
    __syncthreads();

    const f32x4 zf = {0.f, 0.f, 0.f, 0.f};

    // ---- GEMM1: h = gelu(key @ W1^T + b1), (BM x 64); wave owns 16 hidden cols ----
    {
        const int hcol = wave * 16 + lh;
        const float* w1p = W1 + (long)hcol * DK;
        f32x4 acc[BM / 16];
        #pragma unroll
        for (int mt = 0; mt < BM / 16; ++mt) acc[mt] = zf;

        for (int kk = 0; kk < DK / 32; ++kk) {            // 16
            int kofs = kk * 32 + lg * 8;
            bf16x8 bf = loadB8(w1p + kofs);
            #pragma unroll
            for (int mt = 0; mt < BM / 16; ++mt) {
                bf16x8 af = ldsA(kbase, mt * 16 + lh, kofs * 2, DK * 2);
                acc[mt] = __builtin_amdgcn_mfma_f32_16x16x32_bf16(af, bf, acc[mt], 0, 0, 0);
            }
        }
        float bias = b1[hcol];
        #pragma unroll
        for (int mt = 0; mt < BM / 16; ++mt) {
            #pragma unroll
            for (int r = 0; r < 4; ++r) {
                int row = mt * 16 + lg * 4 + r;           // C/D: row=(lane>>4)*4+reg
                float z = acc[mt][r] + bias;
                float g = 0.5f * z * (1.0f + erff(z * 0.70710678f));  // exact GELU
                int byte = (row * DH + hcol) * 2;
                byte ^= (row & 7) << 4;
                *reinterpret_cast<short*>(hbase + byte) = f2bf(g);
            }
        }
    }
    __syncthreads();

    // ---- per wave: 128 output cols, processed as 4 groups of 32 ----
    float facc[BM / 16][4];
    #pragma unroll
    for (int mt = 0; mt < BM / 16; ++mt)
        #pragma unroll
        for (int r = 0; r < 4; ++r) facc[mt][r] = 0.f;

    for (int grp = 0; grp < 4; ++grp) {
        const int nbase = wave * 128 + grp * 32;
        const int n0 = nbase + lh;
        const int n1 = n0 + 16;

        // GEMM2: pred = h @ W2^T (K = 64)
        f32x4 acc2[BM / 16][2];
        #pragma unroll
        for (int mt = 0; mt < BM / 16; ++mt) { acc2[mt][0] = zf; acc2[mt][1] = zf; }
        #pragma unroll
        for (int kk = 0; kk < DH / 32; ++kk) {            // 2
            int kofs = kk * 32 + lg * 8;
            bf16x8 bf0 = loadB8(W2 + (long)n0 * DH + kofs);
            bf16x8 bf1 = loadB8(W2 + (long)n1 * DH + kofs);
            #pragma unroll
            for (int mt = 0; mt < BM / 16; ++mt) {
                bf16x8 af = ldsA(hbase, mt * 16 + lh, kofs * 2, DH * 2);
                acc2[mt][0] = __builtin_amdgcn_mfma_f32_16x16x32_bf16(af, bf0, acc2[mt][0], 0, 0, 0);
                acc2[mt][1] = __builtin_amdgcn_mfma_f32_16x16x32_bf16(af, bf1, acc2[mt][1], 0, 0, 0);
            }
        }

        // GEMM3: z3 = key @ precW^T (K = 512)
        f32x4 acc3[BM / 16][2];
        #pragma unroll
        for (int mt = 0; mt < BM / 16; ++mt) { acc3[mt][0] = zf; acc3[mt][1] = zf; }
        for (int kk = 0; kk < DK / 32; ++kk) {            // 16
            int kofs = kk * 32 + lg * 8;
            bf16x8 bf0 = loadB8(Wp + (long)n0 * DK + kofs);
            bf16x8 bf1 = loadB8(Wp + (long)n1 * DK + kofs);
            #pragma unroll
            for (int mt = 0; mt < BM / 16; ++mt) {
                bf16x8 af = ldsA(kbase, mt * 16 + lh, kofs * 2, DK * 2);
                acc3[mt][0] = __builtin_amdgcn_mfma_f32_16x16x32_bf16(af, bf0, acc3[mt][0], 0, 0, 0);
                acc3[mt][1] = __builtin_amdgcn_mfma_f32_16x16x32_bf16(af, bf1, acc3[mt][1], 0, 0, 0);
            }
        }

        // epilogue for these 32 cols x BM rows
        float b2v0 = b2[n0], b2v1 = b2[n1];
        float pbv0 = pb[n0], pbv1 = pb[n1];
        #pragma unroll
        for (int mt = 0; mt < BM / 16; ++mt) {
            #pragma unroll
            for (int r = 0; r < 4; ++r) {
                int row = mt * 16 + lg * 4 + r;
                long go = (row0 + row) * (long)DV;
                float fsum;
                {
                    float pred = acc2[mt][0][r] + b2v0;
                    float z = acc3[mt][0][r] + pbv0;
                    float prec = fmaxf(z, 0.f) + log1pf(expf(-fabsf(z))) + 0.01f;
                    float err = fminf(fmaxf(value[go + n0] - pred, -3.f), 3.f);
                    outPred[go + n0] = pred;
                    outPrec[go + n0] = prec;
                    outErr[go + n0]  = err;
                    fsum = prec * err * err - logf(prec);
                }
                {
                    float pred = acc2[mt][1][r] + b2v1;
                    float z = acc3[mt][1][r] + pbv1;
                    float prec = fmaxf(z, 0.f) + log1pf(expf(-fabsf(z))) + 0.01f;
                    float err = fminf(fmaxf(value[go + n1] - pred, -3.f), 3.f);
                    outPred[go + n1] = pred;
                    outPrec[go + n1] = prec;
                    outErr[go + n1]  = err;
                    fsum += prec * err * err - logf(prec);
                }
                // reduce across the 16 lanes (same row, different cols)
                #pragma unroll
                for (int off = 1; off < 16; off <<= 1)
                    fsum += __shfl_xor(fsum, off, 64);
                facc[mt][r] += fsum;
            }
        }
    }

    // combine per-wave partials for F (deterministic, no FP atomics)
    #pragma unroll
    for (int mt = 0; mt < BM / 16; ++mt)
        #pragma unroll
        for (int r = 0; r < 4; ++r)
            if (lh == 0) fpart[wave][mt * 16 + lg * 4 + r] = facc[mt][r];
    __syncthreads();
    if (tid < BM) {
        float s = fpart[0][tid] + fpart[1][tid] + fpart[2][tid] + fpart[3][tid];
        outF[row0 + tid] = s * (1.0f / 512.0f);
    }
}

extern "C" void kernel_launch(void* const* d_in, const int* in_sizes, int n_in,
                              void* d_out, int out_size, void* d_ws, size_t ws_size,
                              hipStream_t stream) {
    const float* key   = (const float*)d_in[0];
    const float* value = (const float*)d_in[1];
    const float* W1    = (const float*)d_in[2];
    const float* b1    = (const float*)d_in[3];
    const float* W2    = (const float*)d_in[4];
    const float* b2    = (const float*)d_in[5];
    const float* Wp    = (const float*)d_in[6];
    const float* pb    = (const float*)d_in[7];

    float* outF    = (float*)d_out;
    float* outPred = outF + BATCH;
    float* outPrec = outPred + (long)BATCH * DV;
    float* outErr  = outPrec + (long)BATCH * DV;

    dim3 grid(BATCH / BM);
    fused_free_energy<<<grid, 256, 0, stream>>>(key, value, W1, b1, W2, b2, Wp, pb,
                                                outF, outPred, outPrec, outErr);
}

// Round 2
// 467.298 us; speedup vs baseline: 1.6472x; 1.6472x over previous
//
#include <hip/hip_runtime.h>
#include <hip/hip_bf16.h>

#define BATCH 65536
#define DK 512
#define DV 512
#define DH 64
#define BM 64

typedef __attribute__((ext_vector_type(8))) short bf16x8;
typedef __attribute__((ext_vector_type(4))) float f32x4;

__device__ __forceinline__ short f2bf(float f) {
    union { __hip_bfloat16 h; short s; } u;
    u.h = __float2bfloat16(f);
    return u.s;
}

// load 8 consecutive f32 and convert to a bf16x8 MFMA fragment (fallback path)
__device__ __forceinline__ bf16x8 loadB8f32(const float* __restrict__ p) {
    float4 a = *reinterpret_cast<const float4*>(p);
    float4 b = *reinterpret_cast<const float4*>(p + 4);
    bf16x8 r;
    r[0] = f2bf(a.x); r[1] = f2bf(a.y); r[2] = f2bf(a.z); r[3] = f2bf(a.w);
    r[4] = f2bf(b.x); r[5] = f2bf(b.y); r[6] = f2bf(b.z); r[7] = f2bf(b.w);
    return r;
}

template<bool PRE>
__device__ __forceinline__ bf16x8 loadB(const float* __restrict__ fp,
                                        const short* __restrict__ bp) {
    if constexpr (PRE) return *reinterpret_cast<const bf16x8*>(bp);
    else               return loadB8f32(fp);
}

// swizzled LDS A-fragment read: 16B at (row, kbyte), byte ^= (row&7)<<4
__device__ __forceinline__ bf16x8 ldsA(const char* base, int row, int kbyte, int stride) {
    int byte = row * stride + kbyte;
    byte ^= (row & 7) << 4;
    return *reinterpret_cast<const bf16x8*>(base + byte);
}

// ---- prep: convert W1 (64x512), W2 (512x64), Wp (512x512) f32 -> bf16 in ws ----
__global__ __launch_bounds__(256) void conv_weights(
    const float* __restrict__ W1, const float* __restrict__ W2,
    const float* __restrict__ Wp, short* __restrict__ ws)
{
    int i = blockIdx.x * 256 + threadIdx.x;       // 81920 threads x 4 elems
    long off = (long)i * 4;
    const float* src;
    if (off < 32768)       src = W1 + off;
    else if (off < 65536)  src = W2 + (off - 32768);
    else                   src = Wp + (off - 65536);
    float4 v = *reinterpret_cast<const float4*>(src);
    short4 s;
    s.x = f2bf(v.x); s.y = f2bf(v.y); s.z = f2bf(v.z); s.w = f2bf(v.w);
    *reinterpret_cast<short4*>(ws + off) = s;
}

template<bool PRE>
__global__ __launch_bounds__(256) void fused_free_energy(
    const float* __restrict__ key, const float* __restrict__ value,
    const float* __restrict__ W1, const float* __restrict__ b1,
    const float* __restrict__ W2, const float* __restrict__ b2,
    const float* __restrict__ Wp, const float* __restrict__ pb,
    const short* __restrict__ W1b, const short* __restrict__ W2b,
    const short* __restrict__ Wpb,
    float* __restrict__ outF, float* __restrict__ outPred,
    float* __restrict__ outPrec, float* __restrict__ outErr)
{
    __shared__ short keybS[BM * DK];   // 64 KB, bf16, XOR-swizzled rows
    __shared__ short hbS[BM * DH];     // 8 KB, bf16, XOR-swizzled rows
    __shared__ float fpart[4][BM];     // per-wave row partials of F

    char* kbase = reinterpret_cast<char*>(keybS);
    char* hbase = reinterpret_cast<char*>(hbS);

    const int tid  = threadIdx.x;
    const int wave = tid >> 6;
    const int lane = tid & 63;
    const int lh   = lane & 15;   // 0..15
    const int lg   = lane >> 4;   // 0..3
    const long row0 = (long)blockIdx.x * BM;

    // ---- stage key tile (BM x DK) f32 -> bf16 into swizzled LDS ----
    {
        const float4* kin = reinterpret_cast<const float4*>(key + row0 * DK);
        #pragma unroll
        for (int i = 0; i < (BM * DK / 4) / 256; ++i) {   // 32 iters
            int idx = i * 256 + tid;
            int r  = idx >> 7;       // DK/4 = 128 float4 per row
            int c4 = idx & 127;
            float4 v = kin[idx];
            short4 s;
            s.x = f2bf(v.x); s.y = f2bf(v.y); s.z = f2bf(v.z); s.w = f2bf(v.w);
            int byte = (r * DK + c4 * 4) * 2;
            byte ^= (r & 7) << 4;
            *reinterpret_cast<short4*>(kbase + byte) = s;
        }
    }
    __syncthreads();

    const f32x4 zf = {0.f, 0.f, 0.f, 0.f};

    // ---- GEMM1: h = gelu(key @ W1^T + b1), (BM x 64); wave owns 16 hidden cols ----
    {
        const int hcol = wave * 16 + lh;
        const float* w1p = W1  + (long)hcol * DK;
        const short* w1b = W1b + (long)hcol * DK;
        f32x4 acc[BM / 16];
        #pragma unroll
        for (int mt = 0; mt < BM / 16; ++mt) acc[mt] = zf;

        #pragma unroll
        for (int kk = 0; kk < DK / 32; ++kk) {            // 16, fully unrolled
            int kofs = kk * 32 + lg * 8;
            bf16x8 bf = loadB<PRE>(w1p + kofs, w1b + kofs);
            #pragma unroll
            for (int mt = 0; mt < BM / 16; ++mt) {
                bf16x8 af = ldsA(kbase, mt * 16 + lh, kofs * 2, DK * 2);
                acc[mt] = __builtin_amdgcn_mfma_f32_16x16x32_bf16(af, bf, acc[mt], 0, 0, 0);
            }
        }
        float bias = b1[hcol];
        #pragma unroll
        for (int mt = 0; mt < BM / 16; ++mt) {
            #pragma unroll
            for (int r = 0; r < 4; ++r) {
                int row = mt * 16 + lg * 4 + r;           // C/D: row=(lane>>4)*4+reg
                float z = acc[mt][r] + bias;
                float g = 0.5f * z * (1.0f + erff(z * 0.70710678f));  // exact GELU
                int byte = (row * DH + hcol) * 2;
                byte ^= (row & 7) << 4;
                *reinterpret_cast<short*>(hbase + byte) = f2bf(g);
            }
        }
    }
    __syncthreads();

    // ---- per wave: 128 output cols, processed as 4 groups of 32 ----
    float facc[BM / 16][4];
    #pragma unroll
    for (int mt = 0; mt < BM / 16; ++mt)
        #pragma unroll
        for (int r = 0; r < 4; ++r) facc[mt][r] = 0.f;

    for (int grp = 0; grp < 4; ++grp) {
        const int nbase = wave * 128 + grp * 32;
        const int n0 = nbase + lh;
        const int n1 = n0 + 16;

        // GEMM2: pred = h @ W2^T (K = 64)
        const float* w2p0 = W2  + (long)n0 * DH;
        const float* w2p1 = W2  + (long)n1 * DH;
        const short* w2b0 = W2b + (long)n0 * DH;
        const short* w2b1 = W2b + (long)n1 * DH;
        f32x4 acc2[BM / 16][2];
        #pragma unroll
        for (int mt = 0; mt < BM / 16; ++mt) { acc2[mt][0] = zf; acc2[mt][1] = zf; }
        #pragma unroll
        for (int kk = 0; kk < DH / 32; ++kk) {            // 2
            int kofs = kk * 32 + lg * 8;
            bf16x8 bf0 = loadB<PRE>(w2p0 + kofs, w2b0 + kofs);
            bf16x8 bf1 = loadB<PRE>(w2p1 + kofs, w2b1 + kofs);
            #pragma unroll
            for (int mt = 0; mt < BM / 16; ++mt) {
                bf16x8 af = ldsA(hbase, mt * 16 + lh, kofs * 2, DH * 2);
                acc2[mt][0] = __builtin_amdgcn_mfma_f32_16x16x32_bf16(af, bf0, acc2[mt][0], 0, 0, 0);
                acc2[mt][1] = __builtin_amdgcn_mfma_f32_16x16x32_bf16(af, bf1, acc2[mt][1], 0, 0, 0);
            }
        }

        // GEMM3: z3 = key @ precW^T (K = 512), fully unrolled for load pipelining
        const float* wpp0 = Wp  + (long)n0 * DK;
        const float* wpp1 = Wp  + (long)n1 * DK;
        const short* wpb0 = Wpb + (long)n0 * DK;
        const short* wpb1 = Wpb + (long)n1 * DK;
        f32x4 acc3[BM / 16][2];
        #pragma unroll
        for (int mt = 0; mt < BM / 16; ++mt) { acc3[mt][0] = zf; acc3[mt][1] = zf; }
        #pragma unroll
        for (int kk = 0; kk < DK / 32; ++kk) {            // 16, fully unrolled
            int kofs = kk * 32 + lg * 8;
            bf16x8 bf0 = loadB<PRE>(wpp0 + kofs, wpb0 + kofs);
            bf16x8 bf1 = loadB<PRE>(wpp1 + kofs, wpb1 + kofs);
            #pragma unroll
            for (int mt = 0; mt < BM / 16; ++mt) {
                bf16x8 af = ldsA(kbase, mt * 16 + lh, kofs * 2, DK * 2);
                acc3[mt][0] = __builtin_amdgcn_mfma_f32_16x16x32_bf16(af, bf0, acc3[mt][0], 0, 0, 0);
                acc3[mt][1] = __builtin_amdgcn_mfma_f32_16x16x32_bf16(af, bf1, acc3[mt][1], 0, 0, 0);
            }
        }

        // epilogue for these 32 cols x BM rows
        float b2v0 = b2[n0], b2v1 = b2[n1];
        float pbv0 = pb[n0], pbv1 = pb[n1];
        #pragma unroll
        for (int mt = 0; mt < BM / 16; ++mt) {
            #pragma unroll
            for (int r = 0; r < 4; ++r) {
                int row = mt * 16 + lg * 4 + r;
                long go = (row0 + row) * (long)DV;
                float fsum;
                {
                    float pred = acc2[mt][0][r] + b2v0;
                    float z = acc3[mt][0][r] + pbv0;
                    float prec = fmaxf(z, 0.f) + log1pf(expf(-fabsf(z))) + 0.01f;
                    float err = fminf(fmaxf(value[go + n0] - pred, -3.f), 3.f);
                    outPred[go + n0] = pred;
                    outPrec[go + n0] = prec;
                    outErr[go + n0]  = err;
                    fsum = prec * err * err - logf(prec);
                }
                {
                    float pred = acc2[mt][1][r] + b2v1;
                    float z = acc3[mt][1][r] + pbv1;
                    float prec = fmaxf(z, 0.f) + log1pf(expf(-fabsf(z))) + 0.01f;
                    float err = fminf(fmaxf(value[go + n1] - pred, -3.f), 3.f);
                    outPred[go + n1] = pred;
                    outPrec[go + n1] = prec;
                    outErr[go + n1]  = err;
                    fsum += prec * err * err - logf(prec);
                }
                // reduce across the 16 lanes (same row, different cols)
                #pragma unroll
                for (int off = 1; off < 16; off <<= 1)
                    fsum += __shfl_xor(fsum, off, 64);
                facc[mt][r] += fsum;
            }
        }
    }

    // combine per-wave partials for F (deterministic, no FP atomics)
    #pragma unroll
    for (int mt = 0; mt < BM / 16; ++mt)
        #pragma unroll
        for (int r = 0; r < 4; ++r)
            if (lh == 0) fpart[wave][mt * 16 + lg * 4 + r] = facc[mt][r];
    __syncthreads();
    if (tid < BM) {
        float s = fpart[0][tid] + fpart[1][tid] + fpart[2][tid] + fpart[3][tid];
        outF[row0 + tid] = s * (1.0f / 512.0f);
    }
}

extern "C" void kernel_launch(void* const* d_in, const int* in_sizes, int n_in,
                              void* d_out, int out_size, void* d_ws, size_t ws_size,
                              hipStream_t stream) {
    const float* key   = (const float*)d_in[0];
    const float* value = (const float*)d_in[1];
    const float* W1    = (const float*)d_in[2];
    const float* b1    = (const float*)d_in[3];
    const float* W2    = (const float*)d_in[4];
    const float* b2    = (const float*)d_in[5];
    const float* Wp    = (const float*)d_in[6];
    const float* pb    = (const float*)d_in[7];

    float* outF    = (float*)d_out;
    float* outPred = outF + BATCH;
    float* outPrec = outPred + (long)BATCH * DV;
    float* outErr  = outPrec + (long)BATCH * DV;

    dim3 grid(BATCH / BM);
    const size_t needed = (size_t)(32768 + 32768 + 262144) * sizeof(short); // 655360
    if (ws_size >= needed) {
        short* wsb = (short*)d_ws;
        conv_weights<<<320, 256, 0, stream>>>(W1, W2, Wp, wsb);
        fused_free_energy<true><<<grid, 256, 0, stream>>>(
            key, value, W1, b1, W2, b2, Wp, pb,
            wsb, wsb + 32768, wsb + 65536,
            outF, outPred, outPrec, outErr);
    } else {
        fused_free_energy<false><<<grid, 256, 0, stream>>>(
            key, value, W1, b1, W2, b2, Wp, pb,
            nullptr, nullptr, nullptr,
            outF, outPred, outPrec, outErr);
    }
}

// Round 3
// 300.110 us; speedup vs baseline: 2.5648x; 1.5571x over previous
//
#include <hip/hip_runtime.h>
#include <hip/hip_bf16.h>

#define BATCH 65536
#define DK 512
#define DV 512
#define DH 64
#define BM 64
#define NT (DV / 16)   // 32 column-iterations

typedef __attribute__((ext_vector_type(8))) short bf16x8;
typedef __attribute__((ext_vector_type(4))) float f32x4;

// bf16 weights: [0]=W1 (64x512), [32768]=W2 (512x64), [65536]=Wp (512x512)
__device__ short g_wb[327680];

__device__ __forceinline__ short f2bf(float f) {
    union { __hip_bfloat16 h; short s; } u;
    u.h = __float2bfloat16(f);
    return u.s;
}

__global__ __launch_bounds__(256) void conv_weights(
    const float* __restrict__ W1, const float* __restrict__ W2,
    const float* __restrict__ Wp)
{
    int i = blockIdx.x * 256 + threadIdx.x;     // 81920 threads x 4 elems
    long off = (long)i * 4;
    const float* src;
    if (off < 32768)       src = W1 + off;
    else if (off < 65536)  src = W2 + (off - 32768);
    else                   src = Wp + (off - 65536);
    float4 v = *reinterpret_cast<const float4*>(src);
    short4 s;
    s.x = f2bf(v.x); s.y = f2bf(v.y); s.z = f2bf(v.z); s.w = f2bf(v.w);
    *reinterpret_cast<short4*>(g_wb + off) = s;
}

// ---- reg-staging helpers for a 16-row x 512-col bf16 tile (16 KB) ----
struct StReg { bf16x8 v[4]; };

__device__ __forceinline__ StReg stage_load(const short* __restrict__ src, int tid) {
    StReg s;
    #pragma unroll
    for (int ld = 0; ld < 4; ++ld)
        s.v[ld] = *reinterpret_cast<const bf16x8*>(
            reinterpret_cast<const char*>(src) + ld * 4096 + tid * 16);
    return s;
}

__device__ __forceinline__ void stage_write(char* buf, const StReg& s, int tid) {
    #pragma unroll
    for (int ld = 0; ld < 4; ++ld) {
        int o = ld * 4096 + tid * 16;
        int w = o ^ (((o >> 10) & 7) << 4);   // XOR-swizzle (row period 1024B)
        *reinterpret_cast<bf16x8*>(buf + w) = s.v[ld];
    }
}

// LDS offsets within the 45056-byte block
#define WPA 0
#define WPB 16384
#define W2A 32768
#define W2B (32768 + 2048)
#define HOF 36864

__global__ __launch_bounds__(256, 3) void fused_free_energy(
    const float* __restrict__ key, const float* __restrict__ value,
    const float* __restrict__ b1, const float* __restrict__ b2,
    const float* __restrict__ pb,
    float* __restrict__ outF, float* __restrict__ outPred,
    float* __restrict__ outPrec, float* __restrict__ outErr)
{
    __shared__ __align__(16) char lds[45056];

    const short* W1b = g_wb;
    const short* W2b = g_wb + 32768;
    const short* Wpb = g_wb + 65536;

    const int tid  = threadIdx.x;
    const int wave = tid >> 6;
    const int lane = tid & 63;
    const int lh   = lane & 15;
    const int lg   = lane >> 4;
    const long row0 = (long)blockIdx.x * BM;

    // ---- prologue: key rows -> bf16 register fragments (via LDS, 2 chunks of 32 rows) ----
    bf16x8 kreg[16];
    #pragma unroll
    for (int c = 0; c < 2; ++c) {
        const float4* kin = reinterpret_cast<const float4*>(key + (row0 + c * 32) * DK);
        #pragma unroll
        for (int i = 0; i < 16; ++i) {          // 32 rows x 128 float4 / 256 thr
            int idx = i * 256 + tid;
            int r = idx >> 7, c4 = idx & 127;
            float4 v = kin[idx];
            short4 s;
            s.x = f2bf(v.x); s.y = f2bf(v.y); s.z = f2bf(v.z); s.w = f2bf(v.w);
            int byte = (r * 1024 + c4 * 8) ^ ((r & 7) << 4);
            *reinterpret_cast<short4*>(lds + byte) = s;
        }
        __syncthreads();
        if ((wave >> 1) == c) {
            int rr = (wave & 1) * 16 + lh;
            #pragma unroll
            for (int kk = 0; kk < 16; ++kk) {
                int byte = (rr * 1024 + kk * 64 + lg * 16) ^ ((rr & 7) << 4);
                kreg[kk] = *reinterpret_cast<const bf16x8*>(lds + byte);
            }
        }
        __syncthreads();
    }

    const f32x4 zf = {0.f, 0.f, 0.f, 0.f};

    // ---- GEMM1: h = gelu(key @ W1^T + b1), swapped operands, 4 j-tiles ----
    {
        StReg st = stage_load(W1b, tid);
        stage_write(lds + WPA, st, tid);
        __syncthreads();
        #pragma unroll
        for (int jt = 0; jt < 4; ++jt) {
            char* cbuf = lds + ((jt & 1) ? WPB : WPA);
            StReg nx;
            if (jt < 3) nx = stage_load(W1b + (jt + 1) * 16 * DK, tid);
            f32x4 acc = zf;
            #pragma unroll
            for (int kk = 0; kk < 16; ++kk) {
                int byte = (lh * 1024 + kk * 64 + lg * 16) ^ ((lh & 7) << 4);
                bf16x8 af = *reinterpret_cast<const bf16x8*>(cbuf + byte);
                acc = __builtin_amdgcn_mfma_f32_16x16x32_bf16(af, kreg[kk], acc, 0, 0, 0);
            }
            float4 b1v = *reinterpret_cast<const float4*>(b1 + jt * 16 + lg * 4);
            float b1a[4] = {b1v.x, b1v.y, b1v.z, b1v.w};
            short hs[4];
            #pragma unroll
            for (int r = 0; r < 4; ++r) {
                float z = acc[r] + b1a[r];
                float g = 0.5f * z * (1.0f + erff(z * 0.70710678f));  // exact GELU
                hs[r] = f2bf(g);
            }
            int hb = HOF + wave * 2048 + ((lh * 128 + jt * 32 + lg * 8) ^ ((lh & 7) << 4));
            short4 hv = {hs[0], hs[1], hs[2], hs[3]};
            *reinterpret_cast<short4*>(lds + hb) = hv;
            if (jt < 3) stage_write(lds + ((jt & 1) ? WPA : WPB), nx, tid);
            __syncthreads();
        }
    }

    // read h B-fragments (wave-private region, already barrier'd)
    bf16x8 hreg[2];
    #pragma unroll
    for (int kh = 0; kh < 2; ++kh) {
        int byte = (lh * 128 + kh * 64 + lg * 16) ^ ((lh & 7) << 4);
        hreg[kh] = *reinterpret_cast<const bf16x8*>(lds + HOF + wave * 2048 + byte);
    }

    // ---- main loop: 32 iterations of 16 output columns ----
    {
        StReg st = stage_load(Wpb, tid);
        const bool w2a = (tid < 128);
        bf16x8 w2r;
        if (w2a) w2r = *reinterpret_cast<const bf16x8*>(
                     reinterpret_cast<const char*>(W2b) + tid * 16);
        stage_write(lds + WPA, st, tid);
        if (w2a) {
            int o = tid * 16;
            *reinterpret_cast<bf16x8*>(lds + W2A + (o ^ (((o >> 7) & 7) << 4))) = w2r;
        }
        __syncthreads();

        float facc = 0.f;
        const long grow = row0 + wave * 16 + lh;

        for (int it = 0; it < NT; ++it) {
            char* wpc = lds + ((it & 1) ? WPB : WPA);
            char* w2c = lds + ((it & 1) ? W2B : W2A);

            // issue next-tile global loads early (hide HBM/L2 latency under compute)
            StReg nx; bf16x8 w2n;
            if (it + 1 < NT) {
                nx = stage_load(Wpb + (it + 1) * 16 * DK, tid);
                if (w2a) w2n = *reinterpret_cast<const bf16x8*>(
                             reinterpret_cast<const char*>(W2b) + (it + 1) * 2048 + tid * 16);
            }

            // GEMM3: z3 tile (16n x 16m), A = Wp from LDS, B = key from regs
            f32x4 acc3 = zf;
            #pragma unroll
            for (int kk = 0; kk < 16; ++kk) {
                int byte = (lh * 1024 + kk * 64 + lg * 16) ^ ((lh & 7) << 4);
                bf16x8 af = *reinterpret_cast<const bf16x8*>(wpc + byte);
                acc3 = __builtin_amdgcn_mfma_f32_16x16x32_bf16(af, kreg[kk], acc3, 0, 0, 0);
            }
            // GEMM2: pred tile, A = W2 from LDS, B = h from regs
            f32x4 acc2 = zf;
            #pragma unroll
            for (int kh = 0; kh < 2; ++kh) {
                int byte = (lh * 128 + kh * 64 + lg * 16) ^ ((lh & 7) << 4);
                bf16x8 af = *reinterpret_cast<const bf16x8*>(w2c + byte);
                acc2 = __builtin_amdgcn_mfma_f32_16x16x32_bf16(af, hreg[kh], acc2, 0, 0, 0);
            }

            // epilogue: lane holds 4 consecutive cols (n = it*16 + lg*4 + r) of row m=grow
            int nb = it * 16 + lg * 4;
            float4 b2v = *reinterpret_cast<const float4*>(b2 + nb);
            float4 pbv = *reinterpret_cast<const float4*>(pb + nb);
            float b2a[4] = {b2v.x, b2v.y, b2v.z, b2v.w};
            float pba[4] = {pbv.x, pbv.y, pbv.z, pbv.w};
            long ga = grow * DV + nb;
            float4 val = *reinterpret_cast<const float4*>(value + ga);
            float va[4] = {val.x, val.y, val.z, val.w};
            float prv[4], pcv[4], erv[4];
            #pragma unroll
            for (int r = 0; r < 4; ++r) {
                float pred = acc2[r] + b2a[r];
                float z    = acc3[r] + pba[r];
                float prec = fmaxf(z, 0.f) + log1pf(expf(-fabsf(z))) + 0.01f;
                float err  = fminf(fmaxf(va[r] - pred, -3.f), 3.f);
                prv[r] = pred; pcv[r] = prec; erv[r] = err;
                facc += prec * err * err - logf(prec);
            }
            float4 pr4 = {prv[0], prv[1], prv[2], prv[3]};
            float4 pc4 = {pcv[0], pcv[1], pcv[2], pcv[3]};
            float4 er4 = {erv[0], erv[1], erv[2], erv[3]};
            *reinterpret_cast<float4*>(outPred + ga) = pr4;
            *reinterpret_cast<float4*>(outPrec + ga) = pc4;
            *reinterpret_cast<float4*>(outErr  + ga) = er4;

            // write next tile into the other buffer (its readers finished last barrier)
            if (it + 1 < NT) {
                stage_write(lds + ((it & 1) ? WPA : WPB), nx, tid);
                if (w2a) {
                    int o = tid * 16;
                    *reinterpret_cast<bf16x8*>(
                        lds + ((it & 1) ? W2A : W2B) + (o ^ (((o >> 7) & 7) << 4))) = w2n;
                }
            }
            __syncthreads();
        }

        // F: sum the 4 lg-lanes holding the same row m
        facc += __shfl_xor(facc, 16, 64);
        facc += __shfl_xor(facc, 32, 64);
        if (lane < 16) outF[grow] = facc * (1.0f / 512.0f);
    }
}

extern "C" void kernel_launch(void* const* d_in, const int* in_sizes, int n_in,
                              void* d_out, int out_size, void* d_ws, size_t ws_size,
                              hipStream_t stream) {
    const float* key   = (const float*)d_in[0];
    const float* value = (const float*)d_in[1];
    const float* W1    = (const float*)d_in[2];
    const float* b1    = (const float*)d_in[3];
    const float* W2    = (const float*)d_in[4];
    const float* b2    = (const float*)d_in[5];
    const float* Wp    = (const float*)d_in[6];
    const float* pb    = (const float*)d_in[7];

    float* outF    = (float*)d_out;
    float* outPred = outF + BATCH;
    float* outPrec = outPred + (long)BATCH * DV;
    float* outErr  = outPrec + (long)BATCH * DV;

    conv_weights<<<320, 256, 0, stream>>>(W1, W2, Wp);
    fused_free_energy<<<BATCH / BM, 256, 0, stream>>>(key, value, b1, b2, pb,
                                                      outF, outPred, outPrec, outErr);
}